// Round 1
// baseline (1448.465 us; speedup 1.0000x reference)
//
#include <hip/hip_runtime.h>
#include <math.h>
#include <stdint.h>

#define NIMG   8
#define NA     30000      // H*W*A = 100*100*3
#define PRE_N  2000
#define POST_N 1000
#define NMS_TH 0.7f
#define DCLIP  4.135166556742356f   // log(1000/16)
#define IMGF   1600.0f
#define IMGM1  1599.0f

// ---------------------------------------------------------------------------
// Kernel 1: per-image top-2000 (by logit desc, idx asc), decode, clip, valid.
// ws layout (floats): boxes [8][2000][4] @0, scores [8][2000] @64000,
//                     valid(int) [8][2000] @80000
// ---------------------------------------------------------------------------
__global__ __launch_bounds__(1024) void topk_decode(
    const float* __restrict__ obj,    // [8][3][100][100]
    const float* __restrict__ breg,   // [8][12][100][100]
    float* __restrict__ wsBoxes, float* __restrict__ wsScores,
    int* __restrict__ wsValid)
{
    const int n   = blockIdx.x;
    const int tid = threadIdx.x;

    __shared__ uint64_t sel[2048];        // 16 KB: selected top-2000 (+pad)
    __shared__ uint64_t bnd[4096];        // 32 KB: boundary bin (aliases hist/part)
    __shared__ unsigned int scal[4];      // nsel, nbnd, b_star, c_above

    unsigned int* hist = (unsigned int*)bnd;          // 4096 bins
    unsigned int* part = ((unsigned int*)bnd) + 4096; // 1024 scan partials

    for (int b = tid; b < 4096; b += 1024) hist[b] = 0u;
    if (tid < 4) scal[tid] = 0u;
    __syncthreads();

    const float* objn = obj + n * NA;

    // ---- pass 1: histogram over top-12 bits of sortable key (linear read) ----
    for (int j = tid; j < NA; j += 1024) {
        unsigned int u = __float_as_uint(objn[j]);
        unsigned int k = (u & 0x80000000u) ? ~u : (u | 0x80000000u);
        atomicAdd(&hist[k >> 20], 1u);
    }
    __syncthreads();

    // ---- suffix sums to find boundary bin b* (2000th largest lives there) ----
    unsigned int c0 = hist[tid*4+0], c1 = hist[tid*4+1],
                 c2 = hist[tid*4+2], c3 = hist[tid*4+3];
    part[tid] = c0 + c1 + c2 + c3;
    __syncthreads();
    for (int off = 1; off < 1024; off <<= 1) {
        unsigned int v = (tid + off < 1024) ? part[tid + off] : 0u;
        __syncthreads();
        part[tid] += v;
        __syncthreads();
    }
    unsigned int after = (tid < 1023) ? part[tid + 1] : 0u;
    {
        unsigned int S3 = after + c3;
        unsigned int S2 = S3 + c2;
        unsigned int S1 = S2 + c1;
        unsigned int S0 = S1 + c0;
        if (S3 >= PRE_N && after < PRE_N) { scal[2] = tid*4+3; scal[3] = after; }
        if (S2 >= PRE_N && S3    < PRE_N) { scal[2] = tid*4+2; scal[3] = S3; }
        if (S1 >= PRE_N && S2    < PRE_N) { scal[2] = tid*4+1; scal[3] = S2; }
        if (S0 >= PRE_N && S1    < PRE_N) { scal[2] = tid*4+0; scal[3] = S1; }
    }
    __syncthreads();
    const unsigned int bstar   = scal[2];
    const unsigned int c_above = scal[3];

    // ---- pass 2: compact sure-selected + boundary candidates ----
    // candidate index i = h*300 + w*3 + a; memory index j = a*10000 + (h*100+w)
    for (int j = tid; j < NA; j += 1024) {
        unsigned int u = __float_as_uint(objn[j]);
        unsigned int k = (u & 0x80000000u) ? ~u : (u | 0x80000000u);
        unsigned int bin = k >> 20;
        if (bin < bstar) continue;
        int a = j / 10000, t = j - a * 10000;
        unsigned int i = (unsigned int)(t * 3 + a);
        uint64_t key = (((uint64_t)(~k)) << 32) | (uint64_t)i;
        if (bin > bstar) {
            unsigned int p = atomicAdd(&scal[0], 1u);
            sel[p] = key;
        } else {
            unsigned int p = atomicAdd(&scal[1], 1u);
            if (p < 4096u) bnd[p] = key;   // overwrites hist region (done with it)
        }
    }
    __syncthreads();

    unsigned int nbnd = scal[1]; if (nbnd > 4096u) nbnd = 4096u;
    const unsigned int m = PRE_N - c_above;

    // ---- bitonic sort boundary bin ascending by (~k, idx) ----
    unsigned int P2 = 1; while (P2 < nbnd) P2 <<= 1;
    if (P2 < 2u) P2 = 2u;
    for (unsigned int i = nbnd + tid; i < P2; i += 1024) bnd[i] = ~0ull;
    __syncthreads();
    for (unsigned int ks = 2; ks <= P2; ks <<= 1) {
        for (unsigned int js = ks >> 1; js > 0; js >>= 1) {
            for (unsigned int i = tid; i < P2; i += 1024) {
                unsigned int ix = i ^ js;
                if (ix > i) {
                    uint64_t a0 = bnd[i], a1 = bnd[ix];
                    bool up = ((i & ks) == 0u);
                    bool sw = up ? (a0 > a1) : (a0 < a1);
                    if (sw) { bnd[i] = a1; bnd[ix] = a0; }
                }
            }
            __syncthreads();
        }
    }
    // append top-m of boundary, pad, final sort of 2048
    for (unsigned int r = tid; r < m; r += 1024) sel[c_above + r] = bnd[r];
    for (unsigned int r = PRE_N + tid; r < 2048; r += 1024) sel[r] = ~0ull;
    __syncthreads();
    for (unsigned int ks = 2; ks <= 2048; ks <<= 1) {
        for (unsigned int js = ks >> 1; js > 0; js >>= 1) {
            for (unsigned int i = tid; i < 2048; i += 1024) {
                unsigned int ix = i ^ js;
                if (ix > i) {
                    uint64_t a0 = sel[i], a1 = sel[ix];
                    bool up = ((i & ks) == 0u);
                    bool sw = up ? (a0 > a1) : (a0 < a1);
                    if (sw) { sel[i] = a1; sel[ix] = a0; }
                }
            }
            __syncthreads();
        }
    }

    // ---- decode + clip + valid, write to workspace ----
    for (int r = tid; r < PRE_N; r += 1024) {
        uint64_t key = sel[r];
        unsigned int idx = (unsigned int)key;
        unsigned int k   = ~((unsigned int)(key >> 32));
        unsigned int u   = (k & 0x80000000u) ? (k & 0x7fffffffu) : ~k;
        float logit = __uint_as_float(u);
        float score = 1.0f / (1.0f + expf(-logit));

        int a = idx % 3, t = idx / 3, w = t % 100, h = t / 100;
        const float* bp = breg + n*120000 + (a*4)*10000 + t;
        float dx = bp[0], dy = bp[10000], dw = bp[20000], dh = bp[30000];

        float half = (a == 0) ? 32.0f : ((a == 1) ? 64.0f : 128.0f);
        float cx = w * 16.0f + 8.0f, cy = h * 16.0f + 8.0f;
        float x1 = cx - half, y1 = cy - half, x2 = cx + half, y2 = cy + half;
        float wd = x2 - x1 + 1.0f, hg = y2 - y1 + 1.0f;
        float cxr = x1 + 0.5f * wd, cyr = y1 + 0.5f * hg;
        dw = fminf(dw, DCLIP); dh = fminf(dh, DCLIP);
        float pcx = dx * wd + cxr, pcy = dy * hg + cyr;
        float pw = expf(dw) * wd, ph = expf(dh) * hg;
        float px1 = pcx - 0.5f * pw, py1 = pcy - 0.5f * ph;
        float px2 = pcx + 0.5f * pw - 1.0f, py2 = pcy + 0.5f * ph - 1.0f;
        px1 = fminf(fmaxf(px1, 0.0f), IMGM1);
        px2 = fminf(fmaxf(px2, 0.0f), IMGM1);
        py1 = fminf(fmaxf(py1, 0.0f), IMGM1);
        py2 = fminf(fmaxf(py2, 0.0f), IMGM1);
        float wss = px2 - px1 + 1.0f, hss = py2 - py1 + 1.0f;
        float xc = px1 + wss * 0.5f, yc = py1 + hss * 0.5f;
        int valid = (wss >= 0.0f) && (hss >= 0.0f) && (xc < IMGF) && (yc < IMGF);

        float4 bx = make_float4(px1, py1, px2, py2);
        ((float4*)wsBoxes)[n * PRE_N + r] = bx;
        wsScores[n * PRE_N + r] = score;
        wsValid [n * PRE_N + r] = valid;
    }
}

// ---------------------------------------------------------------------------
// Kernel 2: per-image exact greedy NMS (64-wide tiles) + rank-compact output.
// out layout: boxes [8][1000][4] @0, scores [8][1000] @32000, valid [8][1000] @40000
// ---------------------------------------------------------------------------
__global__ __launch_bounds__(512) void nms_select(
    const float* __restrict__ wsBoxes, const float* __restrict__ wsScores,
    const int* __restrict__ wsValid, float* __restrict__ out)
{
    const int n   = blockIdx.x;
    const int tid = threadIdx.x;

    __shared__ float bx1[PRE_N], by1[PRE_N], bx2[PRE_N], by2[PRE_N];
    __shared__ float bar[PRE_N], bsc[PRE_N];
    __shared__ unsigned char kp[PRE_N];
    __shared__ int sscan[512];

    for (int i = tid; i < PRE_N; i += 512) {
        float4 b = ((const float4*)wsBoxes)[n * PRE_N + i];
        bx1[i] = b.x; by1[i] = b.y; bx2[i] = b.z; by2[i] = b.w;
        bar[i] = (b.z - b.x + 1.0f) * (b.w - b.y + 1.0f);
        bsc[i] = wsScores[n * PRE_N + i];
        kp[i]  = (unsigned char)wsValid[n * PRE_N + i];
    }
    __syncthreads();

    const int ntiles = (PRE_N + 63) / 64;
    for (int tile = 0; tile < ntiles; ++tile) {
        const int base = tile * 64;
        const int end  = min(base + 64, PRE_N);
        // phase 1: intra-tile sequential greedy on wave 0
        if (tid < 64) {
            int j = base + tid;
            bool alive = (j < PRE_N) && kp[j];
            float x1j = 0.f, y1j = 0.f, x2j = 0.f, y2j = 0.f, aj = 0.f;
            if (j < PRE_N) { x1j = bx1[j]; y1j = by1[j]; x2j = bx2[j]; y2j = by2[j]; aj = bar[j]; }
            for (int i = base; i < end; ++i) {
                unsigned long long am = __ballot(alive);
                if ((am >> (i - base)) & 1ull) {
                    if (j > i) {
                        float xx1 = fmaxf(bx1[i], x1j), yy1 = fmaxf(by1[i], y1j);
                        float xx2 = fminf(bx2[i], x2j), yy2 = fminf(by2[i], y2j);
                        float ww = fmaxf(xx2 - xx1 + 1.0f, 0.0f);
                        float hh = fmaxf(yy2 - yy1 + 1.0f, 0.0f);
                        float inter = ww * hh;
                        float iou = inter / (bar[i] + aj - inter);
                        if (iou > NMS_TH) alive = false;
                    }
                }
            }
            if (j < PRE_N) kp[j] = alive ? 1 : 0;
        }
        __syncthreads();
        // phase 2: apply this tile's survivors to all later boxes
        for (int j = end + tid; j < PRE_N; j += 512) {
            if (!kp[j]) continue;
            float x1j = bx1[j], y1j = by1[j], x2j = bx2[j], y2j = by2[j], aj = bar[j];
            for (int i = base; i < end; ++i) {
                if (!kp[i]) continue;
                float xx1 = fmaxf(bx1[i], x1j), yy1 = fmaxf(by1[i], y1j);
                float xx2 = fminf(bx2[i], x2j), yy2 = fminf(by2[i], y2j);
                float ww = fmaxf(xx2 - xx1 + 1.0f, 0.0f);
                float hh = fmaxf(yy2 - yy1 + 1.0f, 0.0f);
                float inter = ww * hh;
                float iou = inter / (bar[i] + aj - inter);
                if (iou > NMS_TH) { kp[j] = 0; break; }
            }
        }
        __syncthreads();
    }

    // ---- prefix scan of keep flags (4 per thread) ----
    int c[4]; const int base4 = tid * 4;
    int lsum = 0;
    for (int q = 0; q < 4; ++q) {
        int i = base4 + q;
        c[q] = (i < PRE_N) ? (int)kp[i] : 0;
        lsum += c[q];
    }
    sscan[tid] = lsum;
    __syncthreads();
    for (int off = 1; off < 512; off <<= 1) {
        int v = (tid >= off) ? sscan[tid - off] : 0;
        __syncthreads();
        sscan[tid] += v;
        __syncthreads();
    }
    const int excl  = sscan[tid] - lsum;
    const int total = sscan[511];

    float* ob  = out + n * POST_N * 4;
    float* osc = out + NIMG * POST_N * 4 + n * POST_N;
    float* ovd = out + NIMG * POST_N * 5 + n * POST_N;

    for (int i = tid; i < POST_N * 4; i += 512) ob[i] = 0.0f;
    for (int i = tid; i < POST_N; i += 512) osc[i] = 0.0f;
    const int lim = min(total, POST_N);
    for (int i = tid; i < POST_N; i += 512) ovd[i] = (i < lim) ? 1.0f : 0.0f;
    __syncthreads();

    int run = excl;
    for (int q = 0; q < 4; ++q) {
        int i = base4 + q;
        if (i < PRE_N && c[q]) {
            if (run < POST_N) {
                ob[run * 4 + 0] = bx1[i];
                ob[run * 4 + 1] = by1[i];
                ob[run * 4 + 2] = bx2[i];
                ob[run * 4 + 3] = by2[i];
                osc[run] = bsc[i];
            }
            run++;
        }
    }
}

extern "C" void kernel_launch(void* const* d_in, const int* in_sizes, int n_in,
                              void* d_out, int out_size, void* d_ws, size_t ws_size,
                              hipStream_t stream) {
    const float* obj  = (const float*)d_in[0];
    const float* breg = (const float*)d_in[1];
    // d_in[2] anchors unused (computed inline, exact in f32)
    float* ws       = (float*)d_ws;
    float* wsBoxes  = ws;                    // 64000 floats
    float* wsScores = ws + 64000;            // 16000 floats
    int*   wsValid  = (int*)(ws + 80000);    // 16000 ints

    topk_decode<<<NIMG, 1024, 0, stream>>>(obj, breg, wsBoxes, wsScores, wsValid);
    nms_select<<<NIMG, 512, 0, stream>>>(wsBoxes, wsScores, wsValid, (float*)d_out);
}

// Round 2
// 846.495 us; speedup vs baseline: 1.7111x; 1.7111x over previous
//
#include <hip/hip_runtime.h>
#include <math.h>
#include <stdint.h>

#define NIMG   8
#define NA     30000      // H*W*A = 100*100*3
#define PRE_N  2000
#define POST_N 1000
#define NMS_TH 0.7f
#define DCLIP  4.135166556742356f   // log(1000/16)
#define IMGF   1600.0f
#define IMGM1  1599.0f

// ws layout (floats): boxes [8][2000][4] @0, scores [8][2000] @64000,
//                     valid(int) [8][2000] @80000,
//                     mask(u64)  [8][2000][32] @96000 floats (byte 384000)

// ---------------------------------------------------------------------------
// Kernel 1: per-image top-2000 (by logit desc, idx asc), decode, clip, valid.
// (unchanged from round 1 — verified bit-exact)
// ---------------------------------------------------------------------------
__global__ __launch_bounds__(1024) void topk_decode(
    const float* __restrict__ obj,    // [8][3][100][100]
    const float* __restrict__ breg,   // [8][12][100][100]
    float* __restrict__ wsBoxes, float* __restrict__ wsScores,
    int* __restrict__ wsValid)
{
    const int n   = blockIdx.x;
    const int tid = threadIdx.x;

    __shared__ uint64_t sel[2048];
    __shared__ uint64_t bnd[4096];
    __shared__ unsigned int scal[4];

    unsigned int* hist = (unsigned int*)bnd;
    unsigned int* part = ((unsigned int*)bnd) + 4096;

    for (int b = tid; b < 4096; b += 1024) hist[b] = 0u;
    if (tid < 4) scal[tid] = 0u;
    __syncthreads();

    const float* objn = obj + n * NA;

    for (int j = tid; j < NA; j += 1024) {
        unsigned int u = __float_as_uint(objn[j]);
        unsigned int k = (u & 0x80000000u) ? ~u : (u | 0x80000000u);
        atomicAdd(&hist[k >> 20], 1u);
    }
    __syncthreads();

    unsigned int c0 = hist[tid*4+0], c1 = hist[tid*4+1],
                 c2 = hist[tid*4+2], c3 = hist[tid*4+3];
    part[tid] = c0 + c1 + c2 + c3;
    __syncthreads();
    for (int off = 1; off < 1024; off <<= 1) {
        unsigned int v = (tid + off < 1024) ? part[tid + off] : 0u;
        __syncthreads();
        part[tid] += v;
        __syncthreads();
    }
    unsigned int after = (tid < 1023) ? part[tid + 1] : 0u;
    {
        unsigned int S3 = after + c3;
        unsigned int S2 = S3 + c2;
        unsigned int S1 = S2 + c1;
        unsigned int S0 = S1 + c0;
        if (S3 >= PRE_N && after < PRE_N) { scal[2] = tid*4+3; scal[3] = after; }
        if (S2 >= PRE_N && S3    < PRE_N) { scal[2] = tid*4+2; scal[3] = S3; }
        if (S1 >= PRE_N && S2    < PRE_N) { scal[2] = tid*4+1; scal[3] = S2; }
        if (S0 >= PRE_N && S1    < PRE_N) { scal[2] = tid*4+0; scal[3] = S1; }
    }
    __syncthreads();
    const unsigned int bstar   = scal[2];
    const unsigned int c_above = scal[3];

    for (int j = tid; j < NA; j += 1024) {
        unsigned int u = __float_as_uint(objn[j]);
        unsigned int k = (u & 0x80000000u) ? ~u : (u | 0x80000000u);
        unsigned int bin = k >> 20;
        if (bin < bstar) continue;
        int a = j / 10000, t = j - a * 10000;
        unsigned int i = (unsigned int)(t * 3 + a);
        uint64_t key = (((uint64_t)(~k)) << 32) | (uint64_t)i;
        if (bin > bstar) {
            unsigned int p = atomicAdd(&scal[0], 1u);
            sel[p] = key;
        } else {
            unsigned int p = atomicAdd(&scal[1], 1u);
            if (p < 4096u) bnd[p] = key;
        }
    }
    __syncthreads();

    unsigned int nbnd = scal[1]; if (nbnd > 4096u) nbnd = 4096u;
    const unsigned int m = PRE_N - c_above;

    unsigned int P2 = 1; while (P2 < nbnd) P2 <<= 1;
    if (P2 < 2u) P2 = 2u;
    for (unsigned int i = nbnd + tid; i < P2; i += 1024) bnd[i] = ~0ull;
    __syncthreads();
    for (unsigned int ks = 2; ks <= P2; ks <<= 1) {
        for (unsigned int js = ks >> 1; js > 0; js >>= 1) {
            for (unsigned int i = tid; i < P2; i += 1024) {
                unsigned int ix = i ^ js;
                if (ix > i) {
                    uint64_t a0 = bnd[i], a1 = bnd[ix];
                    bool up = ((i & ks) == 0u);
                    bool sw = up ? (a0 > a1) : (a0 < a1);
                    if (sw) { bnd[i] = a1; bnd[ix] = a0; }
                }
            }
            __syncthreads();
        }
    }
    for (unsigned int r = tid; r < m; r += 1024) sel[c_above + r] = bnd[r];
    for (unsigned int r = PRE_N + tid; r < 2048; r += 1024) sel[r] = ~0ull;
    __syncthreads();
    for (unsigned int ks = 2; ks <= 2048; ks <<= 1) {
        for (unsigned int js = ks >> 1; js > 0; js >>= 1) {
            for (unsigned int i = tid; i < 2048; i += 1024) {
                unsigned int ix = i ^ js;
                if (ix > i) {
                    uint64_t a0 = sel[i], a1 = sel[ix];
                    bool up = ((i & ks) == 0u);
                    bool sw = up ? (a0 > a1) : (a0 < a1);
                    if (sw) { sel[i] = a1; sel[ix] = a0; }
                }
            }
            __syncthreads();
        }
    }

    for (int r = tid; r < PRE_N; r += 1024) {
        uint64_t key = sel[r];
        unsigned int idx = (unsigned int)key;
        unsigned int k   = ~((unsigned int)(key >> 32));
        unsigned int u   = (k & 0x80000000u) ? (k & 0x7fffffffu) : ~k;
        float logit = __uint_as_float(u);
        float score = 1.0f / (1.0f + expf(-logit));

        int a = idx % 3, t = idx / 3, w = t % 100, h = t / 100;
        const float* bp = breg + n*120000 + (a*4)*10000 + t;
        float dx = bp[0], dy = bp[10000], dw = bp[20000], dh = bp[30000];

        float half = (a == 0) ? 32.0f : ((a == 1) ? 64.0f : 128.0f);
        float cx = w * 16.0f + 8.0f, cy = h * 16.0f + 8.0f;
        float x1 = cx - half, y1 = cy - half, x2 = cx + half, y2 = cy + half;
        float wd = x2 - x1 + 1.0f, hg = y2 - y1 + 1.0f;
        float cxr = x1 + 0.5f * wd, cyr = y1 + 0.5f * hg;
        dw = fminf(dw, DCLIP); dh = fminf(dh, DCLIP);
        float pcx = dx * wd + cxr, pcy = dy * hg + cyr;
        float pw = expf(dw) * wd, ph = expf(dh) * hg;
        float px1 = pcx - 0.5f * pw, py1 = pcy - 0.5f * ph;
        float px2 = pcx + 0.5f * pw - 1.0f, py2 = pcy + 0.5f * ph - 1.0f;
        px1 = fminf(fmaxf(px1, 0.0f), IMGM1);
        px2 = fminf(fmaxf(px2, 0.0f), IMGM1);
        py1 = fminf(fmaxf(py1, 0.0f), IMGM1);
        py2 = fminf(fmaxf(py2, 0.0f), IMGM1);
        float wss = px2 - px1 + 1.0f, hss = py2 - py1 + 1.0f;
        float xc = px1 + wss * 0.5f, yc = py1 + hss * 0.5f;
        int valid = (wss >= 0.0f) && (hss >= 0.0f) && (xc < IMGF) && (yc < IMGF);

        float4 bx = make_float4(px1, py1, px2, py2);
        ((float4*)wsBoxes)[n * PRE_N + r] = bx;
        wsScores[n * PRE_N + r] = score;
        wsValid [n * PRE_N + r] = valid;
    }
}

// ---------------------------------------------------------------------------
// Kernel 2: parallel IoU suppression bit-matrix. block = (image, row-tile of 64).
// mask[n][r][w] bit c set iff j = w*64+c > r, j < 2000, iou(r,j) > thresh.
// ---------------------------------------------------------------------------
__global__ __launch_bounds__(256) void nms_mask(
    const float* __restrict__ wsBoxes, uint64_t* __restrict__ mask)
{
    const int blk  = blockIdx.x;
    const int n    = blk >> 5;
    const int i_t  = blk & 31;
    const int tid  = threadIdx.x;
    const int lane = tid & 63;
    const int wv   = tid >> 6;   // 0..3

    __shared__ float cx1[PRE_N], cy1[PRE_N], cx2[PRE_N], cy2[PRE_N], car[PRE_N];
    __shared__ uint64_t tile[64 * 32];   // [row_local][word]

    for (int i = tid; i < PRE_N; i += 256) {
        float4 b = ((const float4*)wsBoxes)[n * PRE_N + i];
        cx1[i] = b.x; cy1[i] = b.y; cx2[i] = b.z; cy2[i] = b.w;
        car[i] = (b.z - b.x + 1.0f) * (b.w - b.y + 1.0f);
    }
    __syncthreads();

    const int r = i_t * 64 + lane;
    const bool rok = (r < PRE_N);
    float x1r = 0.f, y1r = 0.f, x2r = 0.f, y2r = 0.f, ar = 0.f;
    if (rok) { x1r = cx1[r]; y1r = cy1[r]; x2r = cx2[r]; y2r = cy2[r]; ar = car[r]; }

    for (int j_t = wv; j_t < 32; j_t += 4) {
        uint64_t wbits = 0ull;
        if (rok && j_t >= i_t) {
            const int jbase = j_t * 64;
            for (int c = 0; c < 64; ++c) {
                const int j = jbase + c;
                if (j > r && j < PRE_N) {
                    float xx1 = fmaxf(x1r, cx1[j]), yy1 = fmaxf(y1r, cy1[j]);
                    float xx2 = fminf(x2r, cx2[j]), yy2 = fminf(y2r, cy2[j]);
                    float ww = fmaxf(xx2 - xx1 + 1.0f, 0.0f);
                    float hh = fmaxf(yy2 - yy1 + 1.0f, 0.0f);
                    float inter = ww * hh;
                    float iou = inter / (ar + car[j] - inter);
                    if (iou > NMS_TH) wbits |= (1ull << c);
                }
            }
        }
        tile[lane * 32 + j_t] = wbits;
    }
    __syncthreads();

    uint64_t* dst = mask + ((size_t)n * PRE_N + (size_t)i_t * 64) * 32;
    const int lim = (i_t == 31) ? (16 * 32) : (64 * 32);  // rows >= 2000 don't exist
    for (int q = tid; q < lim; q += 256) dst[q] = tile[q];
}

// ---------------------------------------------------------------------------
// Kernel 3: serial greedy scan over the bit-matrix (register-resident removed
// mask, 16-deep row prefetch) + rank-compact output. One block per image.
// ---------------------------------------------------------------------------
__global__ __launch_bounds__(256) void nms_scan_select(
    const float* __restrict__ wsBoxes, const float* __restrict__ wsScores,
    const int* __restrict__ wsValid, const uint64_t* __restrict__ mask,
    float* __restrict__ out)
{
    const int n   = blockIdx.x;
    const int tid = threadIdx.x;

    __shared__ unsigned char invb[256];
    __shared__ uint64_t keepw[32];
    __shared__ int sscan[256];

    // build "initially removed" (= !valid) bits, 8 boxes per thread
    unsigned int byte = 0u;
    if (tid < PRE_N / 8) {
        for (int q = 0; q < 8; ++q)
            byte |= (wsValid[n * PRE_N + tid * 8 + q] ? 0u : 1u) << q;
    }
    invb[tid] = (unsigned char)byte;
    __syncthreads();

    if (tid < 64) {
        const int lane = tid;
        const int wl   = lane & 31;     // lanes 32..63 mirror 0..31
        uint64_t removed = ((const uint64_t*)invb)[wl];
        const uint64_t* rbase = mask + (size_t)n * PRE_N * 32 + wl;

        uint64_t pf[16];
        for (int d = 0; d < 16; ++d) pf[d] = rbase[(size_t)d * 32];

        for (int i = 0; i < PRE_N; ++i) {
            uint64_t ri = pf[i & 15];
            const int nx = i + 16;
            if (nx < PRE_N) pf[i & 15] = rbase[(size_t)nx * 32];
            const int w = i >> 6, b = i & 63;
            unsigned int lo = (unsigned int)removed;
            unsigned int hi = (unsigned int)(removed >> 32);
            unsigned int s  = (b & 32) ? hi : lo;
            unsigned int wordp = (unsigned int)__builtin_amdgcn_readlane((int)s, w);
            bool dead = (wordp >> (b & 31)) & 1u;
            removed |= dead ? 0ull : ri;
        }
        if (lane < 32) {
            uint64_t kw = ~removed;
            if (wl == 31) kw &= 0xFFFFull;   // rows 2000..2047 don't exist
            keepw[wl] = kw;
        }
    }
    __syncthreads();

    // prefix scan of keep flags, 8 per thread
    int c[8]; const int base8 = tid * 8;
    int lsum = 0;
    for (int q = 0; q < 8; ++q) {
        const int i = base8 + q;
        c[q] = (i < PRE_N) ? (int)((keepw[i >> 6] >> (i & 63)) & 1ull) : 0;
        lsum += c[q];
    }
    sscan[tid] = lsum;
    __syncthreads();
    for (int off = 1; off < 256; off <<= 1) {
        int v = (tid >= off) ? sscan[tid - off] : 0;
        __syncthreads();
        sscan[tid] += v;
        __syncthreads();
    }
    const int excl  = sscan[tid] - lsum;
    const int total = sscan[255];

    float* ob  = out + n * POST_N * 4;
    float* osc = out + NIMG * POST_N * 4 + n * POST_N;
    float* ovd = out + NIMG * POST_N * 5 + n * POST_N;

    for (int i = tid; i < POST_N * 4; i += 256) ob[i] = 0.0f;
    for (int i = tid; i < POST_N; i += 256) osc[i] = 0.0f;
    const int lim = min(total, POST_N);
    for (int i = tid; i < POST_N; i += 256) ovd[i] = (i < lim) ? 1.0f : 0.0f;
    __syncthreads();

    int run = excl;
    for (int q = 0; q < 8; ++q) {
        const int i = base8 + q;
        if (i < PRE_N && c[q]) {
            if (run < POST_N) {
                float4 b = ((const float4*)wsBoxes)[n * PRE_N + i];
                ob[run * 4 + 0] = b.x;
                ob[run * 4 + 1] = b.y;
                ob[run * 4 + 2] = b.z;
                ob[run * 4 + 3] = b.w;
                osc[run] = wsScores[n * PRE_N + i];
            }
            run++;
        }
    }
}

extern "C" void kernel_launch(void* const* d_in, const int* in_sizes, int n_in,
                              void* d_out, int out_size, void* d_ws, size_t ws_size,
                              hipStream_t stream) {
    const float* obj  = (const float*)d_in[0];
    const float* breg = (const float*)d_in[1];
    // d_in[2] anchors unused (computed inline, exact in f32)
    float* ws        = (float*)d_ws;
    float* wsBoxes   = ws;                      // 64000 floats
    float* wsScores  = ws + 64000;              // 16000 floats
    int*   wsValid   = (int*)(ws + 80000);      // 16000 ints
    uint64_t* wsMask = (uint64_t*)(ws + 96000); // 8*2000*32 u64 = 4 MB

    topk_decode<<<NIMG, 1024, 0, stream>>>(obj, breg, wsBoxes, wsScores, wsValid);
    nms_mask<<<NIMG * 32, 256, 0, stream>>>(wsBoxes, wsMask);
    nms_scan_select<<<NIMG, 256, 0, stream>>>(wsBoxes, wsScores, wsValid, wsMask,
                                              (float*)d_out);
}

// Round 3
// 375.260 us; speedup vs baseline: 3.8599x; 2.2558x over previous
//
#include <hip/hip_runtime.h>
#include <math.h>
#include <stdint.h>

#define NIMG   8
#define NA     30000      // H*W*A = 100*100*3
#define PRE_N  2000
#define POST_N 1000
#define NMS_TH 0.7f
#define DCLIP  4.135166556742356f   // log(1000/16)
#define IMGF   1600.0f
#define IMGM1  1599.0f

// ws layout (floats): boxes [8][2000][4] @0, scores [8][2000] @64000,
//                     valid(int) [8][2000] @80000,
//                     mask(u64)  [8][2000][32] @96000 floats (byte 384000)

// ---------------------------------------------------------------------------
// Kernel 1: per-image top-2000 (by logit desc, idx asc), decode, clip, valid.
// (unchanged — verified bit-exact)
// ---------------------------------------------------------------------------
__global__ __launch_bounds__(1024) void topk_decode(
    const float* __restrict__ obj,    // [8][3][100][100]
    const float* __restrict__ breg,   // [8][12][100][100]
    float* __restrict__ wsBoxes, float* __restrict__ wsScores,
    int* __restrict__ wsValid)
{
    const int n   = blockIdx.x;
    const int tid = threadIdx.x;

    __shared__ uint64_t sel[2048];
    __shared__ uint64_t bnd[4096];
    __shared__ unsigned int scal[4];

    unsigned int* hist = (unsigned int*)bnd;
    unsigned int* part = ((unsigned int*)bnd) + 4096;

    for (int b = tid; b < 4096; b += 1024) hist[b] = 0u;
    if (tid < 4) scal[tid] = 0u;
    __syncthreads();

    const float* objn = obj + n * NA;

    for (int j = tid; j < NA; j += 1024) {
        unsigned int u = __float_as_uint(objn[j]);
        unsigned int k = (u & 0x80000000u) ? ~u : (u | 0x80000000u);
        atomicAdd(&hist[k >> 20], 1u);
    }
    __syncthreads();

    unsigned int c0 = hist[tid*4+0], c1 = hist[tid*4+1],
                 c2 = hist[tid*4+2], c3 = hist[tid*4+3];
    part[tid] = c0 + c1 + c2 + c3;
    __syncthreads();
    for (int off = 1; off < 1024; off <<= 1) {
        unsigned int v = (tid + off < 1024) ? part[tid + off] : 0u;
        __syncthreads();
        part[tid] += v;
        __syncthreads();
    }
    unsigned int after = (tid < 1023) ? part[tid + 1] : 0u;
    {
        unsigned int S3 = after + c3;
        unsigned int S2 = S3 + c2;
        unsigned int S1 = S2 + c1;
        unsigned int S0 = S1 + c0;
        if (S3 >= PRE_N && after < PRE_N) { scal[2] = tid*4+3; scal[3] = after; }
        if (S2 >= PRE_N && S3    < PRE_N) { scal[2] = tid*4+2; scal[3] = S3; }
        if (S1 >= PRE_N && S2    < PRE_N) { scal[2] = tid*4+1; scal[3] = S2; }
        if (S0 >= PRE_N && S1    < PRE_N) { scal[2] = tid*4+0; scal[3] = S1; }
    }
    __syncthreads();
    const unsigned int bstar   = scal[2];
    const unsigned int c_above = scal[3];

    for (int j = tid; j < NA; j += 1024) {
        unsigned int u = __float_as_uint(objn[j]);
        unsigned int k = (u & 0x80000000u) ? ~u : (u | 0x80000000u);
        unsigned int bin = k >> 20;
        if (bin < bstar) continue;
        int a = j / 10000, t = j - a * 10000;
        unsigned int i = (unsigned int)(t * 3 + a);
        uint64_t key = (((uint64_t)(~k)) << 32) | (uint64_t)i;
        if (bin > bstar) {
            unsigned int p = atomicAdd(&scal[0], 1u);
            sel[p] = key;
        } else {
            unsigned int p = atomicAdd(&scal[1], 1u);
            if (p < 4096u) bnd[p] = key;
        }
    }
    __syncthreads();

    unsigned int nbnd = scal[1]; if (nbnd > 4096u) nbnd = 4096u;
    const unsigned int m = PRE_N - c_above;

    unsigned int P2 = 1; while (P2 < nbnd) P2 <<= 1;
    if (P2 < 2u) P2 = 2u;
    for (unsigned int i = nbnd + tid; i < P2; i += 1024) bnd[i] = ~0ull;
    __syncthreads();
    for (unsigned int ks = 2; ks <= P2; ks <<= 1) {
        for (unsigned int js = ks >> 1; js > 0; js >>= 1) {
            for (unsigned int i = tid; i < P2; i += 1024) {
                unsigned int ix = i ^ js;
                if (ix > i) {
                    uint64_t a0 = bnd[i], a1 = bnd[ix];
                    bool up = ((i & ks) == 0u);
                    bool sw = up ? (a0 > a1) : (a0 < a1);
                    if (sw) { bnd[i] = a1; bnd[ix] = a0; }
                }
            }
            __syncthreads();
        }
    }
    for (unsigned int r = tid; r < m; r += 1024) sel[c_above + r] = bnd[r];
    for (unsigned int r = PRE_N + tid; r < 2048; r += 1024) sel[r] = ~0ull;
    __syncthreads();
    for (unsigned int ks = 2; ks <= 2048; ks <<= 1) {
        for (unsigned int js = ks >> 1; js > 0; js >>= 1) {
            for (unsigned int i = tid; i < 2048; i += 1024) {
                unsigned int ix = i ^ js;
                if (ix > i) {
                    uint64_t a0 = sel[i], a1 = sel[ix];
                    bool up = ((i & ks) == 0u);
                    bool sw = up ? (a0 > a1) : (a0 < a1);
                    if (sw) { sel[i] = a1; sel[ix] = a0; }
                }
            }
            __syncthreads();
        }
    }

    for (int r = tid; r < PRE_N; r += 1024) {
        uint64_t key = sel[r];
        unsigned int idx = (unsigned int)key;
        unsigned int k   = ~((unsigned int)(key >> 32));
        unsigned int u   = (k & 0x80000000u) ? (k & 0x7fffffffu) : ~k;
        float logit = __uint_as_float(u);
        float score = 1.0f / (1.0f + expf(-logit));

        int a = idx % 3, t = idx / 3, w = t % 100, h = t / 100;
        const float* bp = breg + n*120000 + (a*4)*10000 + t;
        float dx = bp[0], dy = bp[10000], dw = bp[20000], dh = bp[30000];

        float half = (a == 0) ? 32.0f : ((a == 1) ? 64.0f : 128.0f);
        float cx = w * 16.0f + 8.0f, cy = h * 16.0f + 8.0f;
        float x1 = cx - half, y1 = cy - half, x2 = cx + half, y2 = cy + half;
        float wd = x2 - x1 + 1.0f, hg = y2 - y1 + 1.0f;
        float cxr = x1 + 0.5f * wd, cyr = y1 + 0.5f * hg;
        dw = fminf(dw, DCLIP); dh = fminf(dh, DCLIP);
        float pcx = dx * wd + cxr, pcy = dy * hg + cyr;
        float pw = expf(dw) * wd, ph = expf(dh) * hg;
        float px1 = pcx - 0.5f * pw, py1 = pcy - 0.5f * ph;
        float px2 = pcx + 0.5f * pw - 1.0f, py2 = pcy + 0.5f * ph - 1.0f;
        px1 = fminf(fmaxf(px1, 0.0f), IMGM1);
        px2 = fminf(fmaxf(px2, 0.0f), IMGM1);
        py1 = fminf(fmaxf(py1, 0.0f), IMGM1);
        py2 = fminf(fmaxf(py2, 0.0f), IMGM1);
        float wss = px2 - px1 + 1.0f, hss = py2 - py1 + 1.0f;
        float xc = px1 + wss * 0.5f, yc = py1 + hss * 0.5f;
        int valid = (wss >= 0.0f) && (hss >= 0.0f) && (xc < IMGF) && (yc < IMGF);

        float4 bx = make_float4(px1, py1, px2, py2);
        ((float4*)wsBoxes)[n * PRE_N + r] = bx;
        wsScores[n * PRE_N + r] = score;
        wsValid [n * PRE_N + r] = valid;
    }
}

// ---------------------------------------------------------------------------
// Kernel 2: parallel IoU suppression bit-matrix. block = (image, row-tile of 64).
// mask[n][r][w] bit c set iff j = w*64+c > r, j < 2000, iou(r,j) > thresh.
// ---------------------------------------------------------------------------
__global__ __launch_bounds__(256) void nms_mask(
    const float* __restrict__ wsBoxes, uint64_t* __restrict__ mask)
{
    const int blk  = blockIdx.x;
    const int n    = blk >> 5;
    const int i_t  = blk & 31;
    const int tid  = threadIdx.x;
    const int lane = tid & 63;
    const int wv   = tid >> 6;   // 0..3

    __shared__ float cx1[PRE_N], cy1[PRE_N], cx2[PRE_N], cy2[PRE_N], car[PRE_N];
    __shared__ uint64_t tile[64 * 32];   // [row_local][word]

    for (int i = tid; i < PRE_N; i += 256) {
        float4 b = ((const float4*)wsBoxes)[n * PRE_N + i];
        cx1[i] = b.x; cy1[i] = b.y; cx2[i] = b.z; cy2[i] = b.w;
        car[i] = (b.z - b.x + 1.0f) * (b.w - b.y + 1.0f);
    }
    __syncthreads();

    const int r = i_t * 64 + lane;
    const bool rok = (r < PRE_N);
    float x1r = 0.f, y1r = 0.f, x2r = 0.f, y2r = 0.f, ar = 0.f;
    if (rok) { x1r = cx1[r]; y1r = cy1[r]; x2r = cx2[r]; y2r = cy2[r]; ar = car[r]; }

    for (int j_t = wv; j_t < 32; j_t += 4) {
        uint64_t wbits = 0ull;
        if (rok && j_t >= i_t) {
            const int jbase = j_t * 64;
            for (int c = 0; c < 64; ++c) {
                const int j = jbase + c;
                if (j > r && j < PRE_N) {
                    float xx1 = fmaxf(x1r, cx1[j]), yy1 = fmaxf(y1r, cy1[j]);
                    float xx2 = fminf(x2r, cx2[j]), yy2 = fminf(y2r, cy2[j]);
                    float ww = fmaxf(xx2 - xx1 + 1.0f, 0.0f);
                    float hh = fmaxf(yy2 - yy1 + 1.0f, 0.0f);
                    float inter = ww * hh;
                    float iou = inter / (ar + car[j] - inter);
                    if (iou > NMS_TH) wbits |= (1ull << c);
                }
            }
        }
        tile[lane * 32 + j_t] = wbits;
    }
    __syncthreads();

    uint64_t* dst = mask + ((size_t)n * PRE_N + (size_t)i_t * 64) * 32;
    const int lim = (i_t == 31) ? (16 * 32) : (64 * 32);  // rows >= 2000 don't exist
    for (int q = tid; q < lim; q += 256) dst[q] = tile[q];
}

// ---------------------------------------------------------------------------
// Kernel 3: serial greedy scan over the bit-matrix. Prefetch ring has STATIC
// indices (unroll 32) so it lives in VGPRs, 32 loads in flight. One wave
// scans; whole block compacts.
// ---------------------------------------------------------------------------
__global__ __launch_bounds__(256) void nms_scan_select(
    const float* __restrict__ wsBoxes, const float* __restrict__ wsScores,
    const int* __restrict__ wsValid, const uint64_t* __restrict__ mask,
    float* __restrict__ out)
{
    const int n   = blockIdx.x;
    const int tid = threadIdx.x;

    __shared__ unsigned char invb[256];
    __shared__ uint64_t keepw[32];
    __shared__ int sscan[256];

    // build "initially removed" (= !valid) bits, 8 boxes per thread
    unsigned int byte = 0u;
    if (tid < PRE_N / 8) {
        for (int q = 0; q < 8; ++q)
            byte |= (wsValid[n * PRE_N + tid * 8 + q] ? 0u : 1u) << q;
    }
    invb[tid] = (unsigned char)byte;
    __syncthreads();

    if (tid < 64) {
        const int lane = tid;
        const int wl   = lane & 31;     // lanes 32..63 mirror 0..31
        uint64_t removed = ((const uint64_t*)invb)[wl];
        const uint64_t* rbase = mask + (size_t)n * PRE_N * 32 + wl;

        uint64_t pf[32];
        #pragma unroll
        for (int d = 0; d < 32; ++d) pf[d] = rbase[(size_t)d * 32];

        for (int ib = 0; ib < 2048; ib += 32) {
            #pragma unroll
            for (int d = 0; d < 32; ++d) {
                const int i  = ib + d;
                uint64_t ri  = pf[d];
                const int nx = i + 32;
                if (nx < PRE_N) pf[d] = rbase[(size_t)nx * 32];
                if (i < PRE_N) {
                    const int w = i >> 6, b = i & 63;
                    unsigned int lo = (unsigned int)removed;
                    unsigned int hi = (unsigned int)(removed >> 32);
                    unsigned int s  = (b & 32) ? hi : lo;
                    unsigned int wordp =
                        (unsigned int)__builtin_amdgcn_readlane((int)s, w);
                    bool dead = (wordp >> (b & 31)) & 1u;
                    removed |= dead ? 0ull : ri;
                }
            }
        }
        if (lane < 32) {
            uint64_t kw = ~removed;
            if (wl == 31) kw &= 0xFFFFull;   // rows 2000..2047 don't exist
            keepw[wl] = kw;
        }
    }
    __syncthreads();

    // prefix scan of keep flags, 8 per thread
    int c[8]; const int base8 = tid * 8;
    int lsum = 0;
    for (int q = 0; q < 8; ++q) {
        const int i = base8 + q;
        c[q] = (i < PRE_N) ? (int)((keepw[i >> 6] >> (i & 63)) & 1ull) : 0;
        lsum += c[q];
    }
    sscan[tid] = lsum;
    __syncthreads();
    for (int off = 1; off < 256; off <<= 1) {
        int v = (tid >= off) ? sscan[tid - off] : 0;
        __syncthreads();
        sscan[tid] += v;
        __syncthreads();
    }
    const int excl  = sscan[tid] - lsum;
    const int total = sscan[255];

    float* ob  = out + n * POST_N * 4;
    float* osc = out + NIMG * POST_N * 4 + n * POST_N;
    float* ovd = out + NIMG * POST_N * 5 + n * POST_N;

    for (int i = tid; i < POST_N * 4; i += 256) ob[i] = 0.0f;
    for (int i = tid; i < POST_N; i += 256) osc[i] = 0.0f;
    const int lim = min(total, POST_N);
    for (int i = tid; i < POST_N; i += 256) ovd[i] = (i < lim) ? 1.0f : 0.0f;
    __syncthreads();

    int run = excl;
    for (int q = 0; q < 8; ++q) {
        const int i = base8 + q;
        if (i < PRE_N && c[q]) {
            if (run < POST_N) {
                float4 b = ((const float4*)wsBoxes)[n * PRE_N + i];
                ob[run * 4 + 0] = b.x;
                ob[run * 4 + 1] = b.y;
                ob[run * 4 + 2] = b.z;
                ob[run * 4 + 3] = b.w;
                osc[run] = wsScores[n * PRE_N + i];
            }
            run++;
        }
    }
}

extern "C" void kernel_launch(void* const* d_in, const int* in_sizes, int n_in,
                              void* d_out, int out_size, void* d_ws, size_t ws_size,
                              hipStream_t stream) {
    const float* obj  = (const float*)d_in[0];
    const float* breg = (const float*)d_in[1];
    // d_in[2] anchors unused (computed inline, exact in f32)
    float* ws        = (float*)d_ws;
    float* wsBoxes   = ws;                      // 64000 floats
    float* wsScores  = ws + 64000;              // 16000 floats
    int*   wsValid   = (int*)(ws + 80000);      // 16000 ints
    uint64_t* wsMask = (uint64_t*)(ws + 96000); // 8*2000*32 u64 = 4 MB

    topk_decode<<<NIMG, 1024, 0, stream>>>(obj, breg, wsBoxes, wsScores, wsValid);
    nms_mask<<<NIMG * 32, 256, 0, stream>>>(wsBoxes, wsMask);
    nms_scan_select<<<NIMG, 256, 0, stream>>>(wsBoxes, wsScores, wsValid, wsMask,
                                              (float*)d_out);
}